// Round 11
// baseline (490.796 us; speedup 1.0000x reference)
//
#include <hip/hip_runtime.h>
#include <math.h>

#define FF 256
#define CC 100000
#define PMARG 0.2f
#define NMARG 0.3f
#define NGB 1563                 // gemm blocks, 64 cols each (4 waves x 16)
#define W_A 0                    // ws floats: A-pack bf16 frags (32KB)
#define W_GRAM 8192              // Gram 64x64 f32
#define W_PART 12352             // per-wave exp partials: NGB*4*64 floats
#define NPART (NGB * 4)          // 6252 wave-partials per row

typedef __attribute__((ext_vector_type(8))) short short8;   // 8 bf16 = 4 VGPR
typedef __attribute__((ext_vector_type(4))) float f32x4;

__device__ __forceinline__ float wredf(float v) {
#pragma unroll
    for (int s = 1; s < 64; s <<= 1) v += __shfl_xor(v, s, 64);
    return v;
}
__device__ __forceinline__ short f2bf(float f) {
    unsigned u = __float_as_uint(f);
    unsigned r = (u + 0x7fffu + ((u >> 16) & 1u)) >> 16;
    return (short)r;
}
__device__ __forceinline__ short8 pack8(float4 a, float4 b) {
    short8 o;
    o[0] = f2bf(a.x); o[1] = f2bf(a.y); o[2] = f2bf(a.z); o[3] = f2bf(a.w);
    o[4] = f2bf(b.x); o[5] = f2bf(b.y); o[6] = f2bf(b.z); o[7] = f2bf(b.w);
    return o;
}

// block 0: A-pack; block 1: Gram (f32, accuracy-critical)
__global__ __launch_bounds__(256) void k_prep(const float* __restrict__ in,
                                              float* __restrict__ ws) {
    int tid = threadIdx.x;
    const float4* __restrict__ in4 = (const float4*)in;
    if (blockIdx.x == 0) {
        short8* __restrict__ wsa = (short8*)(ws + W_A);
#pragma unroll
        for (int i = 0; i < 8; ++i) {
            int idx = i * 256 + tid;          // (mt*8+ks)*64 + lane
            int lane = idx & 63;
            int ks = (idx >> 6) & 7;
            int mt = idx >> 9;
            int row = mt * 16 + (lane & 15);
            int kq = ks * 8 + (lane >> 4) * 2;
            wsa[idx] = pack8(in4[row * 64 + kq], in4[row * 64 + kq + 1]);
        }
    } else {
        __shared__ float4 sIn[64 * 64];
#pragma unroll
        for (int i = 0; i < 16; ++i) sIn[i * 256 + tid] = in4[i * 256 + tid];
        __syncthreads();
        int r0 = (tid >> 4) << 2;
        int c0 = (tid & 15) << 2;
        float gacc[4][4];
#pragma unroll
        for (int r = 0; r < 4; ++r)
#pragma unroll
            for (int c = 0; c < 4; ++c) gacc[r][c] = 0.f;
        for (int kq = 0; kq < 64; ++kq) {
            float4 a[4], b[4];
#pragma unroll
            for (int r = 0; r < 4; ++r) a[r] = sIn[(r0 + r) * 64 + kq];
#pragma unroll
            for (int c = 0; c < 4; ++c) b[c] = sIn[(c0 + c) * 64 + kq];
#pragma unroll
            for (int r = 0; r < 4; ++r)
#pragma unroll
                for (int c = 0; c < 4; ++c)
                    gacc[r][c] += a[r].x * b[c].x + a[r].y * b[c].y +
                                  a[r].z * b[c].z + a[r].w * b[c].w;
        }
        float* G = ws + W_GRAM;
#pragma unroll
        for (int r = 0; r < 4; ++r)
#pragma unroll
            for (int c = 0; c < 4; ++c)
                G[(r0 + r) * 64 + (c0 + c)] = gacc[r][c];
    }
}

// BARRIER-FREE GEMM: 4 waves/block, wave = 16 cols x 64 rows, fully
// self-contained: stages its OWN 16 V rows into its OWN LDS quadrant
// (global_load_lds, coalesced, source-XOR bank swizzle), wave-local
// s_waitcnt vmcnt(0), 8 k-steps of {2 ds_read + pack + 4 A-loads + 4 MFMA},
// per-wave exp partials. NO __syncthreads anywhere.
__global__ __launch_bounds__(256) void k_gemm(const float* __restrict__ V,
                                              const float* __restrict__ ws_in,
                                              float* __restrict__ logits,
                                              float* __restrict__ ws) {
    __shared__ float4 sB[4 * 16 * 64];    // 4 wave-quadrants x 16 rows x 1KB
    int tid = threadIdx.x;
    int lane = tid & 63, w = tid >> 6;
    int g = lane >> 4, c4 = lane & 15;
    int col0 = blockIdx.x * 64 + w * 16;

    // ---- stage own 16 rows (each gload_lds: 64 lanes x 16B = one 1KB row) ----
    const float4* __restrict__ V4 = (const float4*)V;
#pragma unroll
    for (int r = 0; r < 16; ++r) {
        int vr = col0 + r;
        if (vr >= CC) vr = CC - 1;
        const float4* src = V4 + (size_t)vr * 64 + (lane ^ (r & 7));
        char* dst = (char*)sB + (size_t)(w * 16 + r) * 1024;   // wave-uniform
        __builtin_amdgcn_global_load_lds(
            (const __attribute__((address_space(1))) void*)src,
            (__attribute__((address_space(3))) void*)dst, 16, 0, 0);
    }
    asm volatile("s_waitcnt vmcnt(0)" ::: "memory");   // wave-local drain
    __builtin_amdgcn_sched_barrier(0);

    // ---- MFMA main loop: lane's B row = its fragment col (c4) ----
    const short8* __restrict__ ap = (const short8*)(ws_in + W_A);
    const float4* __restrict__ myrow = sB + (size_t)(w * 16 + c4) * 64;
    int m = c4 & 7;
    f32x4 acc[4];
#pragma unroll
    for (int mt = 0; mt < 4; ++mt) acc[mt] = (f32x4){0.f, 0.f, 0.f, 0.f};
#pragma unroll
    for (int ks = 0; ks < 8; ++ks) {
        int u = ks * 8 + g * 2;
        float4 b0 = myrow[u ^ m];
        float4 b1 = myrow[(u + 1) ^ m];
        short8 bf = pack8(b0, b1);
#pragma unroll
        for (int mt = 0; mt < 4; ++mt) {
            short8 a = ap[(mt * 8 + ks) * 64 + lane];   // L1/L2-hot, coalesced
            acc[mt] = __builtin_amdgcn_mfma_f32_16x16x32_bf16(a, bf, acc[mt], 0, 0, 0);
        }
    }

    // ---- epilogue: logits stores + per-wave exp partials (no cross-wave) ----
    int col = col0 + c4;
    bool cv = col < CC;
    float* __restrict__ P = ws + W_PART + (size_t)(blockIdx.x * 4 + w) * 64;
#pragma unroll
    for (int mt = 0; mt < 4; ++mt)
#pragma unroll
        for (int r = 0; r < 4; ++r) {
            int row = mt * 16 + g * 4 + r;
            float lg = acc[mt][r];
            if (cv) logits[(size_t)row * CC + col] = lg;
            float e = cv ? expf(lg) : 0.f;              // |logit| <= ~19, safe
            e += __shfl_xor(e, 1, 64); e += __shfl_xor(e, 2, 64);
            e += __shfl_xor(e, 4, 64); e += __shfl_xor(e, 8, 64);
            if (c4 == 0) P[row] = e;                    // deterministic
        }
}

__device__ __forceinline__ bool mask_at(const void* p, int idx, int mode) {
    if (mode == 0) return ((const int*)p)[idx] != 0;
    if (mode == 1) return ((const float*)p)[idx] != 0.f;
    return ((const unsigned char*)p)[idx] != 0;
}

// 1 block x 256 threads: parallel partial-combine (merged k_comb), stage
// G + masks into LDS, wave 0 runs the scalar tail
__global__ __launch_bounds__(256) void k_final(const int* __restrict__ targets,
                                               const void* __restrict__ pmask,
                                               const void* __restrict__ nmask,
                                               const float* __restrict__ logits,
                                               const float* __restrict__ ws,
                                               float* __restrict__ out) {
    __shared__ float sSe[256];
    __shared__ float sG[4096];
    __shared__ char sPM[16384];
    __shared__ char sNM[16384];
    __shared__ int sMode;
    int tid = threadIdx.x;

    // phase 0: exp-partial combine, 4 parts per row, coalesced 256B reads
    {
        int row = tid & 63, part = tid >> 6;
        const float* __restrict__ P = ws + W_PART;
        float s = 0.f;
        for (int i = part; i < NPART; i += 4) s += P[(size_t)i * 64 + row];
        sSe[tid] = s;
    }

    // early-issue per-row scalars
    float myLogit = 0.f;
    if (tid < 64) {
        int tgt = targets[tid];
        myLogit = logits[(size_t)tid * CC + tgt];
    }

    // stage G coalesced
    {
        const float4* __restrict__ G4 = (const float4*)(ws + W_GRAM);
        float4* sG4 = (float4*)sG;
#pragma unroll
        for (int i = 0; i < 4; ++i) sG4[tid + i * 256] = G4[tid + i * 256];
    }

    // mask layout detect (identical semantics to prior rounds)
    if (tid < 64) {
        const unsigned int* pw = (const unsigned int*)pmask;
        int okInt = 1, okFlt = 1;
#pragma unroll
        for (int i = 0; i < 16; ++i) {
            unsigned int wv = pw[tid * 16 + i];
            okInt = okInt && (wv <= 1u);
            okFlt = okFlt && (wv == 0u || wv == 0x3f800000u);
        }
        int mode = __all(okInt) ? 0 : (__all(okFlt) ? 1 : 2);
        if (tid == 0) sMode = mode;
    }
    __syncthreads();
    int mode = sMode;
    int mq = (mode == 2) ? 256 : 1024;
    for (int i = tid; i < mq; i += 256) {
        ((float4*)sPM)[i] = ((const float4*)pmask)[i];
        ((float4*)sNM)[i] = ((const float4*)nmask)[i];
    }
    __syncthreads();
    if (tid >= 64) return;

    int lane = tid;
    float se = sSe[lane] + sSe[64 + lane] + sSe[128 + lane] + sSe[192 + lane];
    float lse = logf(se);
    float nll = lse - myLogit;

    float rinv = rsqrtf(sG[lane * 64 + lane]);

    float minp = INFINITY, maxthd = -INFINITY;
    for (int j = 0; j < 64; ++j) {
        float rj = __shfl(rinv, j, 64);
        float sim = sG[lane * 64 + j] * rinv * rj;
        sim = fminf(1.f, fmaxf(-1.f, sim));
        if (j != lane) {
            bool pm = mask_at(sPM, lane * 64 + j, mode);
            float ps = pm ? sim : 2.0f;
            minp = fminf(minp, ps);
            maxthd = fmaxf(maxthd, pm ? sim : -2.0f);   // sentinel 2.0 -> -2.0
        }
    }
    float n_thrd = minp - NMARG;
    float p_thrd = maxthd - PMARG;

    float hps = 0.f, hns = 0.f, hpc = 0.f, hnc = 0.f;
    for (int j = 0; j < 64; ++j) {
        float rj = __shfl(rinv, j, 64);
        float sim = sG[lane * 64 + j] * rinv * rj;
        sim = fminf(1.f, fmaxf(-1.f, sim));
        if (j != lane) {
            bool pm = mask_at(sPM, lane * 64 + j, mode);
            bool nm = mask_at(sNM, lane * 64 + j, mode);
            float ps = pm ? sim : 2.0f;
            float ns = nm ? sim : 2.0f;
            if (ps < p_thrd) { hps += log1pf(expf(-ps)); hpc += 1.f; }
            if (ns < n_thrd) { hns += log1pf(expf(-ns)); hnc += 1.f; }
        }
    }

    float snll = wredf(nll);
    float shps = wredf(hps);
    float shns = wredf(hns);
    float shpc = wredf(hpc);
    float shnc = wredf(hnc);
    if (lane == 0) {
        float bu = snll * (1.f / 64.f);
        float hp = shpc > 0.f ? shps / shpc : 0.f;
        float hn = shnc > 0.f ? shns / shnc : 0.f;
        out[0] = bu + hp + hn;
    }
}

extern "C" void kernel_launch(void* const* d_in, const int* in_sizes, int n_in,
                              void* d_out, int out_size, void* d_ws, size_t ws_size,
                              hipStream_t stream) {
    const float* inputs = (const float*)d_in[0];
    const int* targets  = (const int*)d_in[1];
    const void* pmask   = d_in[2];
    const void* nmask   = d_in[3];
    const float* V      = (const float*)d_in[4];
    float* out = (float*)d_out;      // out[0] = loss
    float* logits = out + 1;         // out[1..] = logits [64][100000] row-major
    float* ws = (float*)d_ws;        // A-pack | Gram | per-wave partials

    hipLaunchKernelGGL(k_prep, dim3(2), dim3(256), 0, stream, inputs, ws);
    hipLaunchKernelGGL(k_gemm, dim3(NGB), dim3(256), 0, stream,
                       V, ws, logits, ws);
    hipLaunchKernelGGL(k_final, dim3(1), dim3(256), 0, stream,
                       targets, pmask, nmask, logits, ws, out);
}

// Round 12
// 116.599 us; speedup vs baseline: 4.2093x; 4.2093x over previous
//
#include <hip/hip_runtime.h>
#include <math.h>

#define FF 256
#define CC 100000
#define PMARG 0.2f
#define NMARG 0.3f
#define NB2 3125                 // gemm blocks: 2 col-tiles x 16 cols (6250*16==CC)
#define W_A 0                    // ws floats: A-pack bf16 frags (32KB)
#define W_GRAM 8192              // Gram 64x64 f32
#define W_SE 12288               // 64 row exp-sums
#define W_PART 12352             // per-block exp partials: NB2*64 floats

typedef __attribute__((ext_vector_type(8))) short short8;   // 8 bf16 = 4 VGPR
typedef __attribute__((ext_vector_type(4))) float f32x4;

__device__ __forceinline__ float wredf(float v) {
#pragma unroll
    for (int s = 1; s < 64; s <<= 1) v += __shfl_xor(v, s, 64);
    return v;
}
__device__ __forceinline__ short f2bf(float f) {
    unsigned u = __float_as_uint(f);
    unsigned r = (u + 0x7fffu + ((u >> 16) & 1u)) >> 16;
    return (short)r;
}
__device__ __forceinline__ short8 pack8(float4 a, float4 b) {
    short8 o;
    o[0] = f2bf(a.x); o[1] = f2bf(a.y); o[2] = f2bf(a.z); o[3] = f2bf(a.w);
    o[4] = f2bf(b.x); o[5] = f2bf(b.y); o[6] = f2bf(b.z); o[7] = f2bf(b.w);
    return o;
}

// block 0: A-pack; block 1: Gram (f32, accuracy-critical)
__global__ __launch_bounds__(256) void k_prep(const float* __restrict__ in,
                                              float* __restrict__ ws) {
    int tid = threadIdx.x;
    const float4* __restrict__ in4 = (const float4*)in;
    if (blockIdx.x == 0) {
        short8* __restrict__ wsa = (short8*)(ws + W_A);
#pragma unroll
        for (int i = 0; i < 8; ++i) {
            int idx = i * 256 + tid;          // (mt*8+ks)*64 + lane
            int lane = idx & 63;
            int ks = (idx >> 6) & 7;
            int mt = idx >> 9;
            int row = mt * 16 + (lane & 15);
            int kq = ks * 8 + (lane >> 4) * 2;
            wsa[idx] = pack8(in4[row * 64 + kq], in4[row * 64 + kq + 1]);
        }
    } else {
        __shared__ float4 sIn[64 * 64];
#pragma unroll
        for (int i = 0; i < 16; ++i) sIn[i * 256 + tid] = in4[i * 256 + tid];
        __syncthreads();
        int r0 = (tid >> 4) << 2;
        int c0 = (tid & 15) << 2;
        float gacc[4][4];
#pragma unroll
        for (int r = 0; r < 4; ++r)
#pragma unroll
            for (int c = 0; c < 4; ++c) gacc[r][c] = 0.f;
        for (int kq = 0; kq < 64; ++kq) {
            float4 a[4], b[4];
#pragma unroll
            for (int r = 0; r < 4; ++r) a[r] = sIn[(r0 + r) * 64 + kq];
#pragma unroll
            for (int c = 0; c < 4; ++c) b[c] = sIn[(c0 + c) * 64 + kq];
#pragma unroll
            for (int r = 0; r < 4; ++r)
#pragma unroll
                for (int c = 0; c < 4; ++c)
                    gacc[r][c] += a[r].x * b[c].x + a[r].y * b[c].y +
                                  a[r].z * b[c].z + a[r].w * b[c].w;
        }
        float* G = ws + W_GRAM;
#pragma unroll
        for (int r = 0; r < 4; ++r)
#pragma unroll
            for (int c = 0; c < 4; ++c)
                G[(r0 + r) * 64 + (c0 + c)] = gacc[r][c];
    }
}

// Streaming GEMM, no V staging: B-fragments loaded straight from V (f32)
// into 64 VGPRs BEFORE the MFMA loop (R10-gemm2 code shape, measured ~24us
// with prepacked source). Per instr: 16 rows x fully-consumed 128B lines.
// 4 waves/block; wave = 16 cols (one MFMA tile) x 32 rows. One tiny barrier
// at the end for the per-block exp partial.
__global__ __launch_bounds__(256, 4) void k_gemm2f(const float* __restrict__ V,
                                                   const float* __restrict__ ws_in,
                                                   float* __restrict__ logits,
                                                   float* __restrict__ ws) {
    __shared__ float sW[64][2];
    int tid = threadIdx.x;
    int lane = tid & 63, w = tid >> 6;
    int ctl = w & 1, rh = w >> 1;          // col-tile-local, row-half
    int ct = blockIdx.x * 2 + ctl;         // 0..6249, all fully valid
    int g = lane >> 4, c4 = lane & 15;
    int col = ct * 16 + c4;

    // ---- all 16 B loads up front: fragment-shaped f32 gather from V ----
    // lane reads V[ct*16 + c4][ks*32 + g*8 .. +8] as two float4s
    const float4* __restrict__ vp = (const float4*)V + (size_t)(ct * 16 + c4) * 64;
    float4 bv[8][2];
#pragma unroll
    for (int ks = 0; ks < 8; ++ks) {
        bv[ks][0] = vp[ks * 8 + g * 2];
        bv[ks][1] = vp[ks * 8 + g * 2 + 1];
    }

    const short8* __restrict__ ap =
        (const short8*)(ws_in + W_A) + (size_t)rh * 16 * 64 + lane;

    f32x4 acc0 = {0.f, 0.f, 0.f, 0.f};
    f32x4 acc1 = {0.f, 0.f, 0.f, 0.f};
#pragma unroll
    for (int ks = 0; ks < 8; ++ks) {
        short8 bf = pack8(bv[ks][0], bv[ks][1]);
        short8 a0 = ap[ks * 64];           // L1-hot, coalesced
        short8 a1 = ap[(8 + ks) * 64];
        acc0 = __builtin_amdgcn_mfma_f32_16x16x32_bf16(a0, bf, acc0, 0, 0, 0);
        acc1 = __builtin_amdgcn_mfma_f32_16x16x32_bf16(a1, bf, acc1, 0, 0, 0);
    }

    // ---- epilogue: logits stores + per-block exp partials ----
#pragma unroll
    for (int q = 0; q < 2; ++q) {
        f32x4 a = q ? acc1 : acc0;
#pragma unroll
        for (int r = 0; r < 4; ++r) {
            int row = rh * 32 + q * 16 + g * 4 + r;
            float lg = a[r];
            logits[(size_t)row * CC + col] = lg;
            float e = expf(lg);                    // |logit| <= ~19, safe
            e += __shfl_xor(e, 1, 64); e += __shfl_xor(e, 2, 64);
            e += __shfl_xor(e, 4, 64); e += __shfl_xor(e, 8, 64);
            if (c4 == 0) sW[row][ctl] = e;
        }
    }
    __syncthreads();
    if (tid < 64)
        ws[W_PART + (size_t)blockIdx.x * 64 + tid] = sW[tid][0] + sW[tid][1];
}

// 64 blocks (one per batch row): deterministic reduce of exp partials
__global__ __launch_bounds__(256) void k_comb(const float* __restrict__ ws_in,
                                              float* __restrict__ ws) {
    __shared__ float sS[256];
    int row = blockIdx.x;
    int tid = threadIdx.x;
    const float* __restrict__ P = ws_in + W_PART;
    float s = 0.f;
    for (int b = tid; b < NB2; b += 256) s += P[(size_t)b * 64 + row];
    sS[tid] = s;
    __syncthreads();
    if (tid < 128) sS[tid] += sS[tid + 128];
    __syncthreads();
    if (tid < 64) {
        float v = sS[tid] + sS[tid + 64];
        v = wredf(v);
        if (tid == 0) ws[W_SE + row] = v;
    }
}

__device__ __forceinline__ bool mask_at(const void* p, int idx, int mode) {
    if (mode == 0) return ((const int*)p)[idx] != 0;
    if (mode == 1) return ((const float*)p)[idx] != 0.f;
    return ((const unsigned char*)p)[idx] != 0;
}

// 1 block x 256 threads: stage G + masks into LDS, wave 0 runs the tail
__global__ __launch_bounds__(256) void k_final(const int* __restrict__ targets,
                                               const void* __restrict__ pmask,
                                               const void* __restrict__ nmask,
                                               const float* __restrict__ logits,
                                               const float* __restrict__ ws,
                                               float* __restrict__ out) {
    __shared__ float sG[4096];
    __shared__ char sPM[16384];
    __shared__ char sNM[16384];
    __shared__ int sMode;
    int tid = threadIdx.x;

    float myLogit = 0.f, mySe = 0.f;
    if (tid < 64) {
        int tgt = targets[tid];
        myLogit = logits[(size_t)tid * CC + tgt];
        mySe = ws[W_SE + tid];
    }
    {
        const float4* __restrict__ G4 = (const float4*)(ws + W_GRAM);
        float4* sG4 = (float4*)sG;
#pragma unroll
        for (int i = 0; i < 4; ++i) sG4[tid + i * 256] = G4[tid + i * 256];
    }
    if (tid < 64) {
        const unsigned int* pw = (const unsigned int*)pmask;
        int okInt = 1, okFlt = 1;
#pragma unroll
        for (int i = 0; i < 16; ++i) {
            unsigned int wv = pw[tid * 16 + i];
            okInt = okInt && (wv <= 1u);
            okFlt = okFlt && (wv == 0u || wv == 0x3f800000u);
        }
        int mode = __all(okInt) ? 0 : (__all(okFlt) ? 1 : 2);
        if (tid == 0) sMode = mode;
    }
    __syncthreads();
    int mode = sMode;
    int mq = (mode == 2) ? 256 : 1024;
    for (int i = tid; i < mq; i += 256) {
        ((float4*)sPM)[i] = ((const float4*)pmask)[i];
        ((float4*)sNM)[i] = ((const float4*)nmask)[i];
    }
    __syncthreads();
    if (tid >= 64) return;

    int lane = tid;
    float lse = logf(mySe);
    float nll = lse - myLogit;

    float rinv = rsqrtf(sG[lane * 64 + lane]);

    float minp = INFINITY, maxthd = -INFINITY;
    for (int j = 0; j < 64; ++j) {
        float rj = __shfl(rinv, j, 64);
        float sim = sG[lane * 64 + j] * rinv * rj;
        sim = fminf(1.f, fmaxf(-1.f, sim));
        if (j != lane) {
            bool pm = mask_at(sPM, lane * 64 + j, mode);
            float ps = pm ? sim : 2.0f;
            minp = fminf(minp, ps);
            maxthd = fmaxf(maxthd, pm ? sim : -2.0f);   // sentinel 2.0 -> -2.0
        }
    }
    float n_thrd = minp - NMARG;
    float p_thrd = maxthd - PMARG;

    float hps = 0.f, hns = 0.f, hpc = 0.f, hnc = 0.f;
    for (int j = 0; j < 64; ++j) {
        float rj = __shfl(rinv, j, 64);
        float sim = sG[lane * 64 + j] * rinv * rj;
        sim = fminf(1.f, fmaxf(-1.f, sim));
        if (j != lane) {
            bool pm = mask_at(sPM, lane * 64 + j, mode);
            bool nm = mask_at(sNM, lane * 64 + j, mode);
            float ps = pm ? sim : 2.0f;
            float ns = nm ? sim : 2.0f;
            if (ps < p_thrd) { hps += log1pf(expf(-ps)); hpc += 1.f; }
            if (ns < n_thrd) { hns += log1pf(expf(-ns)); hnc += 1.f; }
        }
    }

    float snll = wredf(nll);
    float shps = wredf(hps);
    float shns = wredf(hns);
    float shpc = wredf(hpc);
    float shnc = wredf(hnc);
    if (lane == 0) {
        float bu = snll * (1.f / 64.f);
        float hp = shpc > 0.f ? shps / shpc : 0.f;
        float hn = shnc > 0.f ? shns / shnc : 0.f;
        out[0] = bu + hp + hn;
    }
}

extern "C" void kernel_launch(void* const* d_in, const int* in_sizes, int n_in,
                              void* d_out, int out_size, void* d_ws, size_t ws_size,
                              hipStream_t stream) {
    const float* inputs = (const float*)d_in[0];
    const int* targets  = (const int*)d_in[1];
    const void* pmask   = d_in[2];
    const void* nmask   = d_in[3];
    const float* V      = (const float*)d_in[4];
    float* out = (float*)d_out;      // out[0] = loss
    float* logits = out + 1;         // out[1..] = logits [64][100000] row-major
    float* ws = (float*)d_ws;        // A-pack | Gram | se | per-block partials

    hipLaunchKernelGGL(k_prep, dim3(2), dim3(256), 0, stream, inputs, ws);
    hipLaunchKernelGGL(k_gemm2f, dim3(NB2), dim3(256), 0, stream,
                       V, ws, logits, ws);
    hipLaunchKernelGGL(k_comb, dim3(64), dim3(256), 0, stream, ws, ws);
    hipLaunchKernelGGL(k_final, dim3(1), dim3(256), 0, stream,
                       targets, pmask, nmask, logits, ws, out);
}

// Round 13
// 102.009 us; speedup vs baseline: 4.8113x; 1.1430x over previous
//
#include <hip/hip_runtime.h>
#include <math.h>

#define FF 256
#define CC 100000
#define PMARG 0.2f
#define NMARG 0.3f
#define NB2 3125                 // gemm blocks: 2 col-tiles x 16 cols (6250*16==CC)
#define W_A 0                    // ws floats: A-pack bf16 frags (32KB)
#define W_GRAM 8192              // Gram 64x64 f32
#define W_SE 12288               // 64 row exp-sums
#define W_PART 12352             // per-block exp partials: NB2*64 floats

typedef __attribute__((ext_vector_type(8))) short short8;   // 8 bf16 = 4 VGPR
typedef __attribute__((ext_vector_type(4))) float f32x4;

__device__ __forceinline__ float wredf(float v) {
#pragma unroll
    for (int s = 1; s < 64; s <<= 1) v += __shfl_xor(v, s, 64);
    return v;
}
__device__ __forceinline__ short f2bf(float f) {
    unsigned u = __float_as_uint(f);
    unsigned r = (u + 0x7fffu + ((u >> 16) & 1u)) >> 16;
    return (short)r;
}
__device__ __forceinline__ short8 pack8(float4 a, float4 b) {
    short8 o;
    o[0] = f2bf(a.x); o[1] = f2bf(a.y); o[2] = f2bf(a.z); o[3] = f2bf(a.w);
    o[4] = f2bf(b.x); o[5] = f2bf(b.y); o[6] = f2bf(b.z); o[7] = f2bf(b.w);
    return o;
}
__device__ __forceinline__ float dot4(float4 a, float4 b) {
    return a.x * b.x + a.y * b.y + a.z * b.z + a.w * b.w;
}

// blocks 0..3: Gram quadrants (32x32 each, f32, accuracy-critical)
// block 4: A-pack into bf16 MFMA fragments
__global__ __launch_bounds__(256) void k_prep(const float* __restrict__ in,
                                              float* __restrict__ ws) {
    int tid = threadIdx.x;
    int b = blockIdx.x;
    const float4* __restrict__ in4 = (const float4*)in;
    if (b == 4) {
        short8* __restrict__ wsa = (short8*)(ws + W_A);
#pragma unroll
        for (int i = 0; i < 8; ++i) {
            int idx = i * 256 + tid;          // (mt*8+ks)*64 + lane
            int lane = idx & 63;
            int ks = (idx >> 6) & 7;
            int mt = idx >> 9;
            int row = mt * 16 + (lane & 15);
            int kq = ks * 8 + (lane >> 4) * 2;
            wsa[idx] = pack8(in4[row * 64 + kq], in4[row * 64 + kq + 1]);
        }
        return;
    }
    __shared__ float4 sIn[64 * 64];       // 64KB inputs
#pragma unroll
    for (int i = 0; i < 16; ++i) sIn[i * 256 + tid] = in4[i * 256 + tid];
    __syncthreads();
    int qr = b >> 1, qc = b & 1;
    int r0 = qr * 32 + (tid >> 4) * 2;
    int c0 = qc * 32 + (tid & 15) * 2;
    float g00 = 0.f, g01 = 0.f, g10 = 0.f, g11 = 0.f;
    for (int kq = 0; kq < 64; ++kq) {
        float4 a0 = sIn[(r0 + 0) * 64 + kq];
        float4 a1 = sIn[(r0 + 1) * 64 + kq];
        float4 b0 = sIn[(c0 + 0) * 64 + kq];
        float4 b1 = sIn[(c0 + 1) * 64 + kq];
        g00 += dot4(a0, b0); g01 += dot4(a0, b1);
        g10 += dot4(a1, b0); g11 += dot4(a1, b1);
    }
    float* G = ws + W_GRAM;
    G[(r0 + 0) * 64 + c0 + 0] = g00;
    G[(r0 + 0) * 64 + c0 + 1] = g01;
    G[(r0 + 1) * 64 + c0 + 0] = g10;
    G[(r0 + 1) * 64 + c0 + 1] = g11;
}

// Streaming GEMM, no V staging. All 16 B-loads issued as NAMED registers with
// a sched_barrier(0) fence so the compiler CANNOT sink them into the loop
// (R12's VGPR=32 showed it did exactly that). Compiler then inserts counted
// vmcnt waits per use -> pipelined consumption. 4 waves/block; wave = 16 cols
// x 32 rows. launch_bounds(256,2) relaxes the VGPR budget so loads stay live.
__global__ __launch_bounds__(256, 2) void k_gemm2f(const float* __restrict__ V,
                                                   const float* __restrict__ ws_in,
                                                   float* __restrict__ logits,
                                                   float* __restrict__ ws) {
    __shared__ float sW[64][2];
    int tid = threadIdx.x;
    int lane = tid & 63, w = tid >> 6;
    int ctl = w & 1, rh = w >> 1;          // col-tile-local, row-half
    int ct = blockIdx.x * 2 + ctl;         // 0..6249, all fully valid
    int g = lane >> 4, c4 = lane & 15;
    int col = ct * 16 + c4;

    // lane reads V[ct*16+c4][ks*32 + g*8 .. +8] : 16 rows x fully-used 128B lines
    const float4* __restrict__ vp =
        (const float4*)V + (size_t)(ct * 16 + c4) * 64 + g * 2;
    float4 b0a = vp[0],  b0b = vp[1];
    float4 b1a = vp[8],  b1b = vp[9];
    float4 b2a = vp[16], b2b = vp[17];
    float4 b3a = vp[24], b3b = vp[25];
    float4 b4a = vp[32], b4b = vp[33];
    float4 b5a = vp[40], b5b = vp[41];
    float4 b6a = vp[48], b6b = vp[49];
    float4 b7a = vp[56], b7b = vp[57];
    __builtin_amdgcn_sched_barrier(0);     // nothing moves across: all issued

    const short8* __restrict__ ap =
        (const short8*)(ws_in + W_A) + (size_t)rh * 16 * 64 + lane;

    f32x4 acc0 = {0.f, 0.f, 0.f, 0.f};
    f32x4 acc1 = {0.f, 0.f, 0.f, 0.f};
#define GSTEP(K, BA, BB)                                                     \
    {                                                                        \
        short8 bf = pack8(BA, BB);                                           \
        short8 a0 = ap[K * 64];                                              \
        short8 a1 = ap[(8 + K) * 64];                                        \
        acc0 = __builtin_amdgcn_mfma_f32_16x16x32_bf16(a0, bf, acc0, 0, 0, 0);\
        acc1 = __builtin_amdgcn_mfma_f32_16x16x32_bf16(a1, bf, acc1, 0, 0, 0);\
    }
    GSTEP(0, b0a, b0b)
    GSTEP(1, b1a, b1b)
    GSTEP(2, b2a, b2b)
    GSTEP(3, b3a, b3b)
    GSTEP(4, b4a, b4b)
    GSTEP(5, b5a, b5b)
    GSTEP(6, b6a, b6b)
    GSTEP(7, b7a, b7b)
#undef GSTEP

    // ---- epilogue: logits stores + per-block exp partials ----
#pragma unroll
    for (int q = 0; q < 2; ++q) {
        f32x4 a = q ? acc1 : acc0;
#pragma unroll
        for (int r = 0; r < 4; ++r) {
            int row = rh * 32 + q * 16 + g * 4 + r;
            float lg = a[r];
            logits[(size_t)row * CC + col] = lg;
            float e = expf(lg);                    // |logit| <= ~19, safe
            e += __shfl_xor(e, 1, 64); e += __shfl_xor(e, 2, 64);
            e += __shfl_xor(e, 4, 64); e += __shfl_xor(e, 8, 64);
            if (c4 == 0) sW[row][ctl] = e;
        }
    }
    __syncthreads();
    if (tid < 64)
        ws[W_PART + (size_t)blockIdx.x * 64 + tid] = sW[tid][0] + sW[tid][1];
}

// 64 blocks (one per batch row): deterministic reduce of exp partials
__global__ __launch_bounds__(256) void k_comb(const float* __restrict__ ws_in,
                                              float* __restrict__ ws) {
    __shared__ float sS[256];
    int row = blockIdx.x;
    int tid = threadIdx.x;
    const float* __restrict__ P = ws_in + W_PART;
    float s = 0.f;
    for (int b = tid; b < NB2; b += 256) s += P[(size_t)b * 64 + row];
    sS[tid] = s;
    __syncthreads();
    if (tid < 128) sS[tid] += sS[tid + 128];
    __syncthreads();
    if (tid < 64) {
        float v = sS[tid] + sS[tid + 64];
        v = wredf(v);
        if (tid == 0) ws[W_SE + row] = v;
    }
}

__device__ __forceinline__ bool mask_at(const void* p, int idx, int mode) {
    if (mode == 0) return ((const int*)p)[idx] != 0;
    if (mode == 1) return ((const float*)p)[idx] != 0.f;
    return ((const unsigned char*)p)[idx] != 0;
}

// 1 block x 256 threads: stage G + masks into LDS, wave 0 runs the tail
__global__ __launch_bounds__(256) void k_final(const int* __restrict__ targets,
                                               const void* __restrict__ pmask,
                                               const void* __restrict__ nmask,
                                               const float* __restrict__ logits,
                                               const float* __restrict__ ws,
                                               float* __restrict__ out) {
    __shared__ float sG[4096];
    __shared__ char sPM[16384];
    __shared__ char sNM[16384];
    __shared__ int sMode;
    int tid = threadIdx.x;

    float myLogit = 0.f, mySe = 0.f;
    if (tid < 64) {
        int tgt = targets[tid];
        myLogit = logits[(size_t)tid * CC + tgt];
        mySe = ws[W_SE + tid];
    }
    {
        const float4* __restrict__ G4 = (const float4*)(ws + W_GRAM);
        float4* sG4 = (float4*)sG;
#pragma unroll
        for (int i = 0; i < 4; ++i) sG4[tid + i * 256] = G4[tid + i * 256];
    }
    if (tid < 64) {
        const unsigned int* pw = (const unsigned int*)pmask;
        int okInt = 1, okFlt = 1;
#pragma unroll
        for (int i = 0; i < 16; ++i) {
            unsigned int wv = pw[tid * 16 + i];
            okInt = okInt && (wv <= 1u);
            okFlt = okFlt && (wv == 0u || wv == 0x3f800000u);
        }
        int mode = __all(okInt) ? 0 : (__all(okFlt) ? 1 : 2);
        if (tid == 0) sMode = mode;
    }
    __syncthreads();
    int mode = sMode;
    int mq = (mode == 2) ? 256 : 1024;
    for (int i = tid; i < mq; i += 256) {
        ((float4*)sPM)[i] = ((const float4*)pmask)[i];
        ((float4*)sNM)[i] = ((const float4*)nmask)[i];
    }
    __syncthreads();
    if (tid >= 64) return;

    int lane = tid;
    float lse = logf(mySe);
    float nll = lse - myLogit;

    float rinv = rsqrtf(sG[lane * 64 + lane]);

    float minp = INFINITY, maxthd = -INFINITY;
    for (int j = 0; j < 64; ++j) {
        float rj = __shfl(rinv, j, 64);
        float sim = sG[lane * 64 + j] * rinv * rj;
        sim = fminf(1.f, fmaxf(-1.f, sim));
        if (j != lane) {
            bool pm = mask_at(sPM, lane * 64 + j, mode);
            float ps = pm ? sim : 2.0f;
            minp = fminf(minp, ps);
            maxthd = fmaxf(maxthd, pm ? sim : -2.0f);   // sentinel 2.0 -> -2.0
        }
    }
    float n_thrd = minp - NMARG;
    float p_thrd = maxthd - PMARG;

    float hps = 0.f, hns = 0.f, hpc = 0.f, hnc = 0.f;
    for (int j = 0; j < 64; ++j) {
        float rj = __shfl(rinv, j, 64);
        float sim = sG[lane * 64 + j] * rinv * rj;
        sim = fminf(1.f, fmaxf(-1.f, sim));
        if (j != lane) {
            bool pm = mask_at(sPM, lane * 64 + j, mode);
            bool nm = mask_at(sNM, lane * 64 + j, mode);
            float ps = pm ? sim : 2.0f;
            float ns = nm ? sim : 2.0f;
            if (ps < p_thrd) { hps += log1pf(expf(-ps)); hpc += 1.f; }
            if (ns < n_thrd) { hns += log1pf(expf(-ns)); hnc += 1.f; }
        }
    }

    float snll = wredf(nll);
    float shps = wredf(hps);
    float shns = wredf(hns);
    float shpc = wredf(hpc);
    float shnc = wredf(hnc);
    if (lane == 0) {
        float bu = snll * (1.f / 64.f);
        float hp = shpc > 0.f ? shps / shpc : 0.f;
        float hn = shnc > 0.f ? shns / shnc : 0.f;
        out[0] = bu + hp + hn;
    }
}

extern "C" void kernel_launch(void* const* d_in, const int* in_sizes, int n_in,
                              void* d_out, int out_size, void* d_ws, size_t ws_size,
                              hipStream_t stream) {
    const float* inputs = (const float*)d_in[0];
    const int* targets  = (const int*)d_in[1];
    const void* pmask   = d_in[2];
    const void* nmask   = d_in[3];
    const float* V      = (const float*)d_in[4];
    float* out = (float*)d_out;      // out[0] = loss
    float* logits = out + 1;         // out[1..] = logits [64][100000] row-major
    float* ws = (float*)d_ws;        // A-pack | Gram | se | per-block partials

    hipLaunchKernelGGL(k_prep, dim3(5), dim3(256), 0, stream, inputs, ws);
    hipLaunchKernelGGL(k_gemm2f, dim3(NB2), dim3(256), 0, stream,
                       V, ws, logits, ws);
    hipLaunchKernelGGL(k_comb, dim3(64), dim3(256), 0, stream, ws, ws);
    hipLaunchKernelGGL(k_final, dim3(1), dim3(256), 0, stream,
                       targets, pmask, nmask, logits, ws, out);
}